// Round 8
// baseline (599.855 us; speedup 1.0000x reference)
//
#include <hip/hip_runtime.h>
#include <hip/hip_cooperative_groups.h>

namespace cg = cooperative_groups;

namespace {

constexpr int kH  = 1024;
constexpr int kW  = 1024;
constexpr int kHW = kH * kW;
constexpr int kSH = 68;           // int(1023/16)+1+2*2
constexpr int kSW = 68;
constexpr int kD  = 8;            // max depth; features uniform [0,1) -> depth <= 8
constexpr int kT3 = kSH * kSW * kD * kD * kD;   // grid cells per channel
// gridA (splat): per-cell TRANSPOSED layout idxT = (b<<6)+(r<<3)+g
// gridB (blur):  per-cell STANDARD  layout idx  = (r<<6)+(g<<3)+b

// 1024 blocks x 256 threads: exactly one 12-float chunk (4 pixels) per thread.
__global__ __launch_bounds__(256) void minmax_kernel(const float* __restrict__ feat,
                                                     float* __restrict__ part) {
    const float4* f4 = (const float4*)feat;
    int c = blockIdx.x * 256 + threadIdx.x;        // chunk index [0, 262144)
    float4 q0 = f4[c * 3], q1 = f4[c * 3 + 1], q2 = f4[c * 3 + 2];
    float mn[3], mx[3];
    mn[0] = fminf(fminf(q0.x, q0.w), fminf(q1.z, q2.y));
    mx[0] = fmaxf(fmaxf(q0.x, q0.w), fmaxf(q1.z, q2.y));
    mn[1] = fminf(fminf(q0.y, q1.x), fminf(q1.w, q2.z));
    mx[1] = fmaxf(fmaxf(q0.y, q1.x), fmaxf(q1.w, q2.z));
    mn[2] = fminf(fminf(q0.z, q1.y), fminf(q2.x, q2.w));
    mx[2] = fmaxf(fmaxf(q0.z, q1.y), fmaxf(q2.x, q2.w));
    #pragma unroll
    for (int off = 32; off > 0; off >>= 1) {
        #pragma unroll
        for (int ch = 0; ch < 3; ++ch) {
            mn[ch] = fminf(mn[ch], __shfl_down(mn[ch], off, 64));
            mx[ch] = fmaxf(mx[ch], __shfl_down(mx[ch], off, 64));
        }
    }
    __shared__ float smn[4][3], smx[4][3];
    int wave = threadIdx.x >> 6;
    if ((threadIdx.x & 63) == 0) {
        #pragma unroll
        for (int ch = 0; ch < 3; ++ch) { smn[wave][ch] = mn[ch]; smx[wave][ch] = mx[ch]; }
    }
    __syncthreads();
    if (threadIdx.x == 0) {
        #pragma unroll
        for (int ch = 0; ch < 3; ++ch) {
            part[blockIdx.x * 6 + ch]     = fminf(fminf(smn[0][ch], smn[1][ch]), fminf(smn[2][ch], smn[3][ch]));
            part[blockIdx.x * 6 + 3 + ch] = fmaxf(fmaxf(smx[0][ch], smx[1][ch]), fmaxf(smx[2][ch], smx[3][ch]));
        }
    }
}

// Reduces 1024 partials: 4 per thread, then the shfl tree.
__global__ void params_kernel(const float* __restrict__ part, float* __restrict__ hdrF) {
    int t = threadIdx.x;   // 256 threads
    float mn[3] = {1e30f, 1e30f, 1e30f};
    float mx[3] = {-1e30f, -1e30f, -1e30f};
    #pragma unroll
    for (int k = 0; k < 4; ++k) {
        int p = t + k * 256;
        #pragma unroll
        for (int c = 0; c < 3; ++c) {
            mn[c] = fminf(mn[c], part[p * 6 + c]);
            mx[c] = fmaxf(mx[c], part[p * 6 + 3 + c]);
        }
    }
    #pragma unroll
    for (int off = 32; off > 0; off >>= 1) {
        #pragma unroll
        for (int c = 0; c < 3; ++c) {
            mn[c] = fminf(mn[c], __shfl_down(mn[c], off, 64));
            mx[c] = fmaxf(mx[c], __shfl_down(mx[c], off, 64));
        }
    }
    __shared__ float smn[4][3], smx[4][3];
    int wave = t >> 6;
    if ((t & 63) == 0) {
        #pragma unroll
        for (int c = 0; c < 3; ++c) { smn[wave][c] = mn[c]; smx[wave][c] = mx[c]; }
    }
    __syncthreads();
    if (t == 0) {
        int* ip = (int*)(hdrF + 8);
        #pragma unroll
        for (int c = 0; c < 3; ++c) {
            float bmn = fminf(fminf(smn[0][c], smn[1][c]), fminf(smn[2][c], smn[3][c]));
            float bmx = fmaxf(fmaxf(smx[0][c], smx[1][c]), fmaxf(smx[2][c], smx[3][c]));
            float delta = bmx - bmn;                        // fp32 sub, like numpy
            int depth = (int)((double)delta / 0.25) + 1 + 4;
            if (depth > kD) depth = kD;
            if (depth < 1) depth = 1;
            hdrF[c] = bmn;
            ip[c] = depth;
        }
    }
}

// ---- shared phase bodies (identical math to R7; callable from standalone
//      kernels AND the fused cooperative kernel). Each ends with a trailing
//      __syncthreads so grid-stride reuse of the LDS buffer is safe. ----

// Multi-cell privatized splat for one 2x2 cell group (gx,gy = base cell).
// hist must hold 4*1536 floats.
__device__ __forceinline__ void splat_group(int gx, int gy,
                                            const float* __restrict__ feat,
                                            const float* __restrict__ inp,
                                            const float* __restrict__ hdrF,
                                            float* __restrict__ grid,
                                            float* __restrict__ hist) {
    int x0 = 16 * gx - 8, y0 = 16 * gy - 8;
    int xs = x0 < 0 ? 0 : x0, ys = y0 < 0 ? 0 : y0;
    int xe = x0 + 32 > kW ? kW : x0 + 32;
    int ye = y0 + 32 > kH ? kH : y0 + 32;
    int wpix = xe - xs, hpix = ye - ys;
    int npix = wpix * hpix;

    {
        float4 z = make_float4(0.f, 0.f, 0.f, 0.f);
        float4* h4 = (float4*)hist;
        for (int i = threadIdx.x; i < 1536; i += 256) h4[i] = z;
    }
    float m0 = hdrF[0], m1 = hdrF[1], m2 = hdrF[2];
    __syncthreads();

    for (int idx = threadIdx.x; idx < npix; idx += 256) {
        int py, px;
        if (wpix == 32) { py = idx >> 5; px = idx & 31; }
        else            { py = idx / wpix; px = idx - py * wpix; }
        int X = xs + px, Y = ys + py;
        long p = (((long)Y << 10) + X) * 3;
        float f0 = feat[p], f1 = feat[p + 1], f2 = feat[p + 2];
        float v0 = inp[p],  v1 = inp[p + 1],  v2 = inp[p + 2];
        int sr = (int)((f0 - m0) * 4.0f + 0.5f) + 2;   // /0.25 == *4 exact
        int sg = (int)((f1 - m1) * 4.0f + 0.5f) + 2;
        int sb = (int)((f2 - m2) * 4.0f + 0.5f) + 2;
        int cl = ((((Y + 8) >> 4) - gy) << 1) + (((X + 8) >> 4) - gx);
        int ciT = (sb << 6) + (sr << 3) + sg;          // transposed bin directly
        float* hc = hist + cl * 1536;
        atomicAdd(&hc[ciT],        v0);
        atomicAdd(&hc[512 + ciT],  v1);
        atomicAdd(&hc[1024 + ciT], v2);
    }
    __syncthreads();

    const float4* h4 = (const float4*)hist;
    float4* g4 = (float4*)grid;
    #pragma unroll
    for (int cl = 0; cl < 4; ++cl) {
        int cix = gx + (cl & 1), ciy = gy + (cl >> 1);
        if (cix > 64 || ciy > 64) continue;            // ghost cells of the last row/col
        long base4 = ((long)((ciy + 2) * kSW + (cix + 2))) << 7;   // 128 float4 per cell
        for (int j = threadIdx.x; j < 384; j += 256) {
            int ch = j >> 7, id = j & 127;
            g4[(long)ch * (kT3 / 4) + base4 + id] = h4[cl * 384 + ch * 128 + id];
        }
    }
    __syncthreads();   // protect hist re-zero on the next grid-stride iteration
}

// blur body: both _convn outer-iterations for one (ch, rg) column of a cell.
// Fast path inlined with literal (8,8,8) so depth selects constant-fold.
__device__ __forceinline__ void blur_body(float* __restrict__ dst,
                                          const float* __restrict__ src,
                                          const float* __restrict__ Sv,
                                          int cx, int cy, long cbase,
                                          int dr, int dg, int db) {
    int ch = threadIdx.x >> 6;
    int rg = threadIdx.x & 63;
    int r = rg >> 3, g = rg & 7;

    const float* S = Sv + ch * 576;
    auto SV = [&](int b, int l) -> float { return S[b * 72 + l]; };
    auto gsp = [&](int ccy, int ccx, int rr, int gg, int bb) -> float {
        if (ccy < 2 || ccy > 66 || ccx < 2 || ccx > 66) return 0.0f;
        return src[(long)ch * kT3 + (((long)(ccy * kSW + ccx)) << 9) + (bb << 6) + (rr << 3) + gg];
    };

    bool gI = (g >= 1) && (g <= dg - 2);
    bool rI = (r >= 1) && (r <= dr - 2);

    float v[8];
    #pragma unroll
    for (int b = 0; b < 8; ++b) v[b] = SV(b, rg);

    int eHi = db - 1;

    auto o1_end = [&](int e) -> float {
        float Vm, Vp;
        if (gI)      { Vm = SV(e, rg - 1); Vp = SV(e, rg + 1); }
        else if (rI) { Vm = SV(e, rg - 8); Vp = SV(e, rg + 8); }
        else         { Vm = gsp(cy, cx - 1, r, g, e); Vp = gsp(cy, cx + 1, r, g, e); }
        return (Vm + Vp + 2.0f * SV(e, rg)) * 0.25f;
    };
    float o1_lo = o1_end(0);
    float o1_hi = o1_end(eHi);

    float o1[8];
    #pragma unroll
    for (int b = 0; b < 8; ++b) {
        float iv = 0.0f;
        if (b >= 1 && b <= 6) iv = ((v[b - 1] + v[b + 1]) + 2.0f * v[b]) * 0.25f;
        o1[b] = (b >= 1 && b <= db - 2) ? iv : (b == 0 ? o1_lo : (b == eHi ? o1_hi : 0.0f));
    }

    auto out1_in = [&](int r2, int g2, int e) -> float {
        int l2 = (r2 << 3) + g2;
        float C = SV(e, l2);
        float Nm, Np;
        if (g2 >= 1 && g2 <= dg - 2)      { Nm = SV(e, l2 - 1); Np = SV(e, l2 + 1); }
        else if (r2 >= 1 && r2 <= dr - 2) { Nm = SV(e, l2 - 8); Np = SV(e, l2 + 8); }
        else { Nm = gsp(cy, cx - 1, r2, g2, e); Np = gsp(cy, cx + 1, r2, g2, e); }
        return (Nm + Np + 2.0f * C) * 0.25f;
    };
    auto out1_x = [&](int cx2, int e) -> float {
        float C = gsp(cy, cx2, r, g, e);
        float Nm, Np;
        if (cx2 >= 1 && cx2 <= kSW - 2) { Nm = gsp(cy, cx2 - 1, r, g, e); Np = gsp(cy, cx2 + 1, r, g, e); }
        else                            { Nm = gsp(cy - 1, cx2, r, g, e); Np = gsp(cy + 1, cx2, r, g, e); }
        return (Nm + Np + 2.0f * C) * 0.25f;
    };
    auto o2_end = [&](int e, float o1e) -> float {
        float Xm, Xp;
        if (gI)      { Xm = out1_in(r, g - 1, e); Xp = out1_in(r, g + 1, e); }
        else if (rI) { Xm = out1_in(r - 1, g, e); Xp = out1_in(r + 1, g, e); }
        else         { Xm = out1_x(cx - 1, e);    Xp = out1_x(cx + 1, e); }
        return (Xm + Xp + 2.0f * o1e) * 0.25f;
    };
    float o2_lo = o2_end(0, o1_lo);
    float o2_hi = o2_end(eHi, o1_hi);

    float o2[8];
    #pragma unroll
    for (int b = 0; b < 8; ++b) {
        float iv = 0.0f;
        if (b >= 1 && b <= 6) iv = ((o1[b - 1] + o1[b + 1]) + 2.0f * o1[b]) * 0.25f;
        o2[b] = (b >= 1 && b <= db - 2) ? iv : (b == 0 ? o2_lo : (b == eHi ? o2_hi : 0.0f));
    }

    float* dp = dst + (long)ch * kT3 + cbase + (rg << 3);
    *(float4*)dp       = make_float4(o2[0], o2[1], o2[2], o2[3]);
    *(float4*)(dp + 4) = make_float4(o2[4], o2[5], o2[6], o2[7]);
}

// One cell's blur: stage (all threads) + compute (first 192 threads).
// Sv must hold 3*576 floats. Works with blockDim.x in {192, 256}.
__device__ __forceinline__ void blur_cell(int cx, int cy,
                                          float* __restrict__ dst,
                                          const float* __restrict__ src,
                                          const float* __restrict__ hdrF,
                                          float* __restrict__ Sv) {
    const int* ip = (const int*)(hdrF + 8);
    int dr = ip[0], dg = ip[1], db = ip[2];
    long cbase = ((long)(cy * kSW + cx)) << 9;

    {
        const float4* g4 = (const float4*)src;
        for (int i = threadIdx.x; i < 384; i += blockDim.x) {
            int ch = i >> 7, i4 = i & 127;
            float4 q = g4[(long)ch * (kT3 / 4) + (cbase >> 2) + i4];
            int b = i4 >> 4;
            int rg = ((i4 >> 1) & 7) * 8 + (i4 & 1) * 4;
            *(float4*)&Sv[ch * 576 + b * 72 + rg] = q;
        }
    }
    __syncthreads();

    if (threadIdx.x < 192) {
        if (dr == 8 && dg == 8 && db == 8) {
            blur_body(dst, src, Sv, cx, cy, cbase, 8, 8, 8);   // literal depths fold
        } else {
            blur_body(dst, src, Sv, cx, cy, cbase, dr, dg, db);
        }
    }
    __syncthreads();   // protect Sv restage on the next grid-stride iteration
}

// One 16x16 tile's slice. sg must hold 3*4*512+8 floats. Requires 256 threads.
__device__ __forceinline__ void slice_tile(int tx, int ty,
                                           const float* __restrict__ feat,
                                           const float* __restrict__ hdrF,
                                           const float* __restrict__ grid,
                                           float* __restrict__ out,
                                           float* __restrict__ sg) {
    {
        const float4* g4 = (const float4*)grid;
        float4* s4 = (float4*)sg;
        #pragma unroll
        for (int it = 0; it < 2; ++it) {
            int i = threadIdx.x + it * 256;       // float4 index within a channel plane [0,512)
            int cell = i >> 7;                    // 0..3 = (dy<<1)|dx
            int ci4 = i & 127;
            int cy = ty + 2 + (cell >> 1), cx = tx + 2 + (cell & 1);
            long cbase4 = ((long)(cy * kSW + cx)) << 7;   // 128 float4 per cell
            #pragma unroll
            for (int ch = 0; ch < 3; ++ch)
                s4[ch * 512 + i] = g4[(long)ch * (kT3 / 4) + cbase4 + ci4];
        }
    }
    __syncthreads();

    const int* ip = (const int*)(hdrF + 8);
    int d3[3] = {ip[0], ip[1], ip[2]};
    int lx = threadIdx.x & 15, ly = threadIdx.x >> 4;
    int y = (ty << 4) + ly, x = (tx << 4) + lx;
    int p = (y << 10) + x;

    float ya = (float)ly * 0.0625f;   // exact fractional part of y/16
    float xa = (float)lx * 0.0625f;

    int li[3], ri[3];
    float al[3];
    #pragma unroll
    for (int c = 0; c < 3; ++c) {
        float v0 = feat[p * 3 + c] - hdrF[c];
        float sv = v0 * 4.0f + 2.0f;
        int l = (int)sv;
        int dm = d3[c] - 1;
        l = l < 0 ? 0 : (l > dm ? dm : l);
        int rr = l + 1 > dm ? dm : l + 1;
        li[c] = l; ri[c] = rr; al[c] = sv - (float)l;
    }

    float spw[4];
    {
        float wy[2] = {1.0f - ya, ya};
        float wx[2] = {1.0f - xa, xa};
        spw[0] = wy[0] * wx[0]; spw[1] = wy[0] * wx[1];
        spw[2] = wy[1] * wx[0]; spw[3] = wy[1] * wx[1];
    }
    int rs[2] = {li[0], ri[0]}; float wrr[2] = {1.0f - al[0], al[0]};
    int gs[2] = {li[1], ri[1]}; float wgg[2] = {1.0f - al[1], al[1]};
    int bq = li[2];
    float aeff = (ri[2] > li[2]) ? al[2] : 0.0f;

    float acc0 = 0.0f, acc1 = 0.0f, acc2 = 0.0f;
    #pragma unroll
    for (int k = 0; k < 4; ++k) {
        #pragma unroll
        for (int cr = 0; cr < 2; ++cr)
        #pragma unroll
        for (int cg = 0; cg < 2; ++cg) {
            int si = (k << 9) + (rs[cr] << 6) + (gs[cg] << 3) + bq;
            float w = spw[k] * wrr[cr] * wgg[cg];
            float a0 = sg[si],        a1 = sg[si + 1];
            float b0 = sg[2048 + si], b1 = sg[2048 + si + 1];
            float c0 = sg[4096 + si], c1 = sg[4096 + si + 1];
            acc0 += w * (a0 + aeff * (a1 - a0));
            acc1 += w * (b0 + aeff * (b1 - b0));
            acc2 += w * (c0 + aeff * (c1 - c0));
        }
    }
    out[p * 3 + 0] = acc0;
    out[p * 3 + 1] = acc1;
    out[p * 3 + 2] = acc2;
    __syncthreads();   // protect sg restage on the next grid-stride iteration
}

// ---- standalone fallback kernels (R7 shapes) ----
__global__ __launch_bounds__(256) void splat_kernel(const float* __restrict__ feat,
                                                    const float* __restrict__ inp,
                                                    const float* __restrict__ hdrF,
                                                    float* __restrict__ grid) {
    __shared__ __align__(16) float hist[4 * 1536];
    splat_group(blockIdx.x << 1, blockIdx.y << 1, feat, inp, hdrF, grid, hist);
}

__global__ __launch_bounds__(192) void blur2_kernel(float* __restrict__ dst,
                                                    const float* __restrict__ src,
                                                    const float* __restrict__ hdrF) {
    __shared__ __align__(16) float Sv[3 * 576];
    blur_cell(blockIdx.x + 2, blockIdx.y + 2, dst, src, hdrF, Sv);
}

__global__ __launch_bounds__(256) void slice_kernel(const float* __restrict__ feat,
                                                    const float* __restrict__ hdrF,
                                                    const float* __restrict__ grid,
                                                    float* __restrict__ out) {
    __shared__ __align__(16) float sg[3 * 4 * 512 + 8];
    slice_tile(blockIdx.x, blockIdx.y, feat, hdrF, grid, out, sg);
}

// ---- fused cooperative kernel: splat -> blur -> slice with grid.sync()
//      between phases. 1024 blocks x 256 thr = 4 blocks/CU guaranteed by
//      __launch_bounds__(256,4) (128 VGPR cap, 24.6 KB LDS < 160/4 KB).
//      Replaces 2 dispatch drain/launch boundaries with 2 grid barriers. ----
__global__ __launch_bounds__(256, 4) void fused3_kernel(const float* __restrict__ feat,
                                                        const float* __restrict__ inp,
                                                        const float* __restrict__ hdrF,
                                                        float* __restrict__ gA,
                                                        float* __restrict__ gB,
                                                        float* __restrict__ out) {
    __shared__ __align__(16) float lds[3 * 4 * 512 + 8];   // max of the 3 phases
    cg::grid_group gg = cg::this_grid();
    int nb = gridDim.x;

    for (int g = blockIdx.x; g < 33 * 33; g += nb) {
        int by = g / 33, bx = g - by * 33;
        splat_group(bx << 1, by << 1, feat, inp, hdrF, gA, lds);
    }
    __threadfence();
    gg.sync();

    for (int c = blockIdx.x; c < 65 * 65; c += nb) {
        int cy = c / 65, cx = c - cy * 65;
        blur_cell(cx + 2, cy + 2, gB, gA, hdrF, lds);
    }
    __threadfence();
    gg.sync();

    for (int t = blockIdx.x; t < 64 * 64; t += nb) {
        int ty = t >> 6, tx = t & 63;
        slice_tile(tx, ty, feat, hdrF, gB, out, lds);
    }
}

}  // namespace

extern "C" void kernel_launch(void* const* d_in, const int* in_sizes, int n_in,
                              void* d_out, int out_size, void* d_ws, size_t ws_size,
                              hipStream_t stream) {
    const float* feat = (const float*)d_in[0];
    const float* inp  = (const float*)d_in[1];
    float* out = (float*)d_out;

    float* hdrF  = (float*)d_ws;
    float* part  = (float*)((char*)d_ws + 1024);       // 1024 x 6 floats = 24 KB
    float* gridA = (float*)((char*)d_ws + 32768);      // splat, transposed cells
    float* gridB = gridA + 3 * (size_t)kT3;            // blurred, standard cells

    minmax_kernel<<<1024, 256, 0, stream>>>(feat, part);
    params_kernel<<<1, 256, 0, stream>>>(part, hdrF);

    void* kargs[] = {(void*)&feat, (void*)&inp, (void*)&hdrF,
                     (void*)&gridA, (void*)&gridB, (void*)&out};
    hipError_t err = hipLaunchCooperativeKernel((const void*)fused3_kernel,
                                                dim3(1024), dim3(256),
                                                kargs, 0, stream);
    if (err != hipSuccess) {
        (void)hipGetLastError();   // clear error state, fall back to 3 dispatches
        splat_kernel<<<dim3(33, 33), 256, 0, stream>>>(feat, inp, hdrF, gridA);
        blur2_kernel<<<dim3(65, 65), 192, 0, stream>>>(gridB, gridA, hdrF);
        slice_kernel<<<dim3(64, 64), 256, 0, stream>>>(feat, hdrF, gridB, out);
    }
}

// Round 9
// 139.126 us; speedup vs baseline: 4.3116x; 4.3116x over previous
//
#include <hip/hip_runtime.h>

namespace {

constexpr int kH  = 1024;
constexpr int kW  = 1024;
constexpr int kHW = kH * kW;
constexpr int kSH = 68;           // int(1023/16)+1+2*2
constexpr int kSW = 68;
constexpr int kD  = 8;            // max depth; features uniform [0,1) -> depth <= 8
constexpr int kT3 = kSH * kSW * kD * kD * kD;   // grid cells per channel
// gridA (splat): per-cell TRANSPOSED layout idxT = (b<<6)+(r<<3)+g
// gridB (blur):  per-cell STANDARD  layout idx  = (r<<6)+(g<<3)+b

// 1024 blocks x 256 threads: exactly one 12-float chunk (4 pixels) per thread.
__global__ __launch_bounds__(256) void minmax_kernel(const float* __restrict__ feat,
                                                     float* __restrict__ part) {
    const float4* f4 = (const float4*)feat;
    int c = blockIdx.x * 256 + threadIdx.x;        // chunk index [0, 262144)
    float4 q0 = f4[c * 3], q1 = f4[c * 3 + 1], q2 = f4[c * 3 + 2];
    float mn[3], mx[3];
    mn[0] = fminf(fminf(q0.x, q0.w), fminf(q1.z, q2.y));
    mx[0] = fmaxf(fmaxf(q0.x, q0.w), fmaxf(q1.z, q2.y));
    mn[1] = fminf(fminf(q0.y, q1.x), fminf(q1.w, q2.z));
    mx[1] = fmaxf(fmaxf(q0.y, q1.x), fmaxf(q1.w, q2.z));
    mn[2] = fminf(fminf(q0.z, q1.y), fminf(q2.x, q2.w));
    mx[2] = fmaxf(fmaxf(q0.z, q1.y), fmaxf(q2.x, q2.w));
    #pragma unroll
    for (int off = 32; off > 0; off >>= 1) {
        #pragma unroll
        for (int ch = 0; ch < 3; ++ch) {
            mn[ch] = fminf(mn[ch], __shfl_down(mn[ch], off, 64));
            mx[ch] = fmaxf(mx[ch], __shfl_down(mx[ch], off, 64));
        }
    }
    __shared__ float smn[4][3], smx[4][3];
    int wave = threadIdx.x >> 6;
    if ((threadIdx.x & 63) == 0) {
        #pragma unroll
        for (int ch = 0; ch < 3; ++ch) { smn[wave][ch] = mn[ch]; smx[wave][ch] = mx[ch]; }
    }
    __syncthreads();
    if (threadIdx.x == 0) {
        #pragma unroll
        for (int ch = 0; ch < 3; ++ch) {
            part[blockIdx.x * 6 + ch]     = fminf(fminf(smn[0][ch], smn[1][ch]), fminf(smn[2][ch], smn[3][ch]));
            part[blockIdx.x * 6 + 3 + ch] = fmaxf(fmaxf(smx[0][ch], smx[1][ch]), fmaxf(smx[2][ch], smx[3][ch]));
        }
    }
}

// Reduces 1024 partials: 4 per thread, then the shfl tree.
__global__ void params_kernel(const float* __restrict__ part, float* __restrict__ hdrF) {
    int t = threadIdx.x;   // 256 threads
    float mn[3] = {1e30f, 1e30f, 1e30f};
    float mx[3] = {-1e30f, -1e30f, -1e30f};
    #pragma unroll
    for (int k = 0; k < 4; ++k) {
        int p = t + k * 256;
        #pragma unroll
        for (int c = 0; c < 3; ++c) {
            mn[c] = fminf(mn[c], part[p * 6 + c]);
            mx[c] = fmaxf(mx[c], part[p * 6 + 3 + c]);
        }
    }
    #pragma unroll
    for (int off = 32; off > 0; off >>= 1) {
        #pragma unroll
        for (int c = 0; c < 3; ++c) {
            mn[c] = fminf(mn[c], __shfl_down(mn[c], off, 64));
            mx[c] = fmaxf(mx[c], __shfl_down(mx[c], off, 64));
        }
    }
    __shared__ float smn[4][3], smx[4][3];
    int wave = t >> 6;
    if ((t & 63) == 0) {
        #pragma unroll
        for (int c = 0; c < 3; ++c) { smn[wave][c] = mn[c]; smx[wave][c] = mx[c]; }
    }
    __syncthreads();
    if (t == 0) {
        int* ip = (int*)(hdrF + 8);
        #pragma unroll
        for (int c = 0; c < 3; ++c) {
            float bmn = fminf(fminf(smn[0][c], smn[1][c]), fminf(smn[2][c], smn[3][c]));
            float bmx = fmaxf(fmaxf(smx[0][c], smx[1][c]), fmaxf(smx[2][c], smx[3][c]));
            float delta = bmx - bmn;                        // fp32 sub, like numpy
            int depth = (int)((double)delta / 0.25) + 1 + 4;
            if (depth > kD) depth = kD;
            if (depth < 1) depth = 1;
            hdrF[c] = bmn;
            ip[c] = depth;
        }
    }
}

// Privatized splat: one block per INTERIOR cell [2,66]^2. LDS histogram is
// accumulated DIRECTLY in transposed order (b<<6|r<<3|g), so the epilogue is
// a straight float4 copy (384 dwordx4 stores vs 1536 scalar + index math).
// Zero global atomics.
__global__ __launch_bounds__(256) void splat_kernel(const float* __restrict__ feat,
                                                    const float* __restrict__ inp,
                                                    const float* __restrict__ hdrF,
                                                    float* __restrict__ grid) {
    int ix = blockIdx.x, iy = blockIdx.y;          // band index 0..64
    int y0 = (iy == 0) ? 0 : 16 * iy - 8;
    int x0 = (ix == 0) ? 0 : 16 * ix - 8;
    int h = (iy == 0 || iy == 64) ? 8 : 16;
    int w = (ix == 0 || ix == 64) ? 8 : 16;

    __shared__ float acc[3 * 512];
    __shared__ float fS[16 * 48], iS[16 * 48];
    {
        float4 z = make_float4(0.f, 0.f, 0.f, 0.f);
        float4* a4 = (float4*)acc;
        for (int i = threadIdx.x; i < 384; i += 256) a4[i] = z;
    }

    int rowVec = (w * 3) >> 2;                     // float4 per row: 12 or 6
    int nvec = h * rowVec;
    const float4* f4 = (const float4*)(feat + ((long)y0 * kW + x0) * 3);
    const float4* i4 = (const float4*)(inp  + ((long)y0 * kW + x0) * 3);
    for (int t = threadIdx.x; t < nvec; t += 256) {
        int row = t / rowVec, q = t - row * rowVec;
        ((float4*)fS)[row * rowVec + q] = f4[row * (kW * 3 / 4) + q];
        ((float4*)iS)[row * rowVec + q] = i4[row * (kW * 3 / 4) + q];
    }
    __syncthreads();

    int t = threadIdx.x;
    int n = w * h;
    if (t < n) {
        int lx = t & (w - 1);
        int ly = (w == 16) ? (t >> 4) : (t >> 3);
        int o = (ly * w + lx) * 3;
        float v0 = fS[o + 0] - hdrF[0];
        float v1 = fS[o + 1] - hdrF[1];
        float v2 = fS[o + 2] - hdrF[2];
        int sr = (int)(v0 * 4.0f + 0.5f) + 2;   // /0.25 == *4 exact
        int sg = (int)(v1 * 4.0f + 0.5f) + 2;
        int sb = (int)(v2 * 4.0f + 0.5f) + 2;
        int ciT = (sb << 6) + (sr << 3) + sg;   // transposed bin directly
        atomicAdd(&acc[ciT],        iS[o + 0]);
        atomicAdd(&acc[512 + ciT],  iS[o + 1]);
        atomicAdd(&acc[1024 + ciT], iS[o + 2]);
    }
    __syncthreads();

    long base4 = ((long)((iy + 2) * kSW + (ix + 2))) << 7;   // 128 float4 per cell
    const float4* a4 = (const float4*)acc;
    float4* g4 = (float4*)grid;
    for (int j = threadIdx.x; j < 384; j += 256) {
        int ch = j >> 7, idx = j & 127;
        g4[(long)ch * (kT3 / 4) + base4 + idx] = a4[ch * 128 + idx];
    }
}

// blur body: both _convn outer-iterations for one (ch, rg) column of a cell.
// On the wave-uniform fast path it is inlined with literal (8,8,8) so all
// depth-dependent selects and the eHi indexing constant-fold; the runtime
// clone is kept for generality on other data.
__device__ __forceinline__ void blur_body(float* __restrict__ dst,
                                          const float* __restrict__ src,
                                          const float* __restrict__ Sv,
                                          int cx, int cy, long cbase,
                                          int dr, int dg, int db) {
    int ch = threadIdx.x >> 6;
    int rg = threadIdx.x & 63;
    int r = rg >> 3, g = rg & 7;

    const float* S = Sv + ch * 576;
    auto SV = [&](int b, int l) -> float { return S[b * 72 + l]; };
    auto gsp = [&](int ccy, int ccx, int rr, int gg, int bb) -> float {
        if (ccy < 2 || ccy > 66 || ccx < 2 || ccx > 66) return 0.0f;
        return src[(long)ch * kT3 + (((long)(ccy * kSW + ccx)) << 9) + (bb << 6) + (rr << 3) + gg];
    };

    bool gI = (g >= 1) && (g <= dg - 2);
    bool rI = (r >= 1) && (r <= dr - 2);

    float v[8];
    #pragma unroll
    for (int b = 0; b < 8; ++b) v[b] = SV(b, rg);

    int eHi = db - 1;

    auto o1_end = [&](int e) -> float {
        float Vm, Vp;
        if (gI)      { Vm = SV(e, rg - 1); Vp = SV(e, rg + 1); }
        else if (rI) { Vm = SV(e, rg - 8); Vp = SV(e, rg + 8); }
        else         { Vm = gsp(cy, cx - 1, r, g, e); Vp = gsp(cy, cx + 1, r, g, e); }
        return (Vm + Vp + 2.0f * SV(e, rg)) * 0.25f;
    };
    float o1_lo = o1_end(0);
    float o1_hi = o1_end(eHi);

    float o1[8];
    #pragma unroll
    for (int b = 0; b < 8; ++b) {
        float iv = 0.0f;
        if (b >= 1 && b <= 6) iv = ((v[b - 1] + v[b + 1]) + 2.0f * v[b]) * 0.25f;
        o1[b] = (b >= 1 && b <= db - 2) ? iv : (b == 0 ? o1_lo : (b == eHi ? o1_hi : 0.0f));
    }

    auto out1_in = [&](int r2, int g2, int e) -> float {
        int l2 = (r2 << 3) + g2;
        float C = SV(e, l2);
        float Nm, Np;
        if (g2 >= 1 && g2 <= dg - 2)      { Nm = SV(e, l2 - 1); Np = SV(e, l2 + 1); }
        else if (r2 >= 1 && r2 <= dr - 2) { Nm = SV(e, l2 - 8); Np = SV(e, l2 + 8); }
        else { Nm = gsp(cy, cx - 1, r2, g2, e); Np = gsp(cy, cx + 1, r2, g2, e); }
        return (Nm + Np + 2.0f * C) * 0.25f;
    };
    auto out1_x = [&](int cx2, int e) -> float {
        float C = gsp(cy, cx2, r, g, e);
        float Nm, Np;
        if (cx2 >= 1 && cx2 <= kSW - 2) { Nm = gsp(cy, cx2 - 1, r, g, e); Np = gsp(cy, cx2 + 1, r, g, e); }
        else                            { Nm = gsp(cy - 1, cx2, r, g, e); Np = gsp(cy + 1, cx2, r, g, e); }
        return (Nm + Np + 2.0f * C) * 0.25f;
    };
    auto o2_end = [&](int e, float o1e) -> float {
        float Xm, Xp;
        if (gI)      { Xm = out1_in(r, g - 1, e); Xp = out1_in(r, g + 1, e); }
        else if (rI) { Xm = out1_in(r - 1, g, e); Xp = out1_in(r + 1, g, e); }
        else         { Xm = out1_x(cx - 1, e);    Xp = out1_x(cx + 1, e); }
        return (Xm + Xp + 2.0f * o1e) * 0.25f;
    };
    float o2_lo = o2_end(0, o1_lo);
    float o2_hi = o2_end(eHi, o1_hi);

    float o2[8];
    #pragma unroll
    for (int b = 0; b < 8; ++b) {
        float iv = 0.0f;
        if (b >= 1 && b <= 6) iv = ((o1[b - 1] + o1[b + 1]) + 2.0f * o1[b]) * 0.25f;
        o2[b] = (b >= 1 && b <= db - 2) ? iv : (b == 0 ? o2_lo : (b == eHi ? o2_hi : 0.0f));
    }

    // standard layout: this thread's 8 b-values are contiguous at rg*8
    float* dp = dst + (long)ch * kT3 + cbase + (rg << 3);
    *(float4*)dp       = make_float4(o2[0], o2[1], o2[2], o2[3]);
    *(float4*)(dp + 4) = make_float4(o2[4], o2[5], o2[6], o2[7]);
}

// Both _convn outer-iterations, LDS-resident per spatial cell (R6 algorithm).
// gridA is transposed -> staging is a straight float4 copy into the padded
// stencil layout Sv[ch][b (stride 72)][r*8+g]. Output written straight from
// registers to gridB in STANDARD layout (each thread's 8 b-values contiguous).
__global__ __launch_bounds__(192) void blur2_kernel(float* __restrict__ dst,
                                                    const float* __restrict__ src,
                                                    const float* __restrict__ hdrF) {
    int cx = blockIdx.x + 2, cy = blockIdx.y + 2;   // [2,66]
    const int* ip = (const int*)(hdrF + 8);
    int dr = ip[0], dg = ip[1], db = ip[2];

    __shared__ float Sv[3 * 576];   // [ch][b(8) stride 72][rg(64)]
    long cbase = ((long)(cy * kSW + cx)) << 9;

    {
        const float4* g4 = (const float4*)src;
        for (int i = threadIdx.x; i < 384; i += 192) {
            int ch = i >> 7, i4 = i & 127;
            float4 q = g4[(long)ch * (kT3 / 4) + (cbase >> 2) + i4];
            int b = i4 >> 4;
            int rg = ((i4 >> 1) & 7) * 8 + (i4 & 1) * 4;
            *(float4*)&Sv[ch * 576 + b * 72 + rg] = q;
        }
    }
    __syncthreads();

    if (dr == 8 && dg == 8 && db == 8) {
        blur_body(dst, src, Sv, cx, cy, cbase, 8, 8, 8);   // literal depths: selects fold
    } else {
        blur_body(dst, src, Sv, cx, cy, cbase, dr, dg, db);
    }
}

// LDS-staged slice (R4 structure): one block per 16x16 pixel tile, stage 4
// cells x 512 x 3ch (24 KB). Gather uses ADJACENT b-pairs (si, si+1) merged
// into ds_read2_b32 by the compiler, with arithmetic b-lerp (aeff=0 when
// clamped) -> 48 paired reads instead of 96 independent ones.
__global__ __launch_bounds__(256) void slice_kernel(const float* __restrict__ feat,
                                                    const float* __restrict__ hdrF,
                                                    const float* __restrict__ grid,
                                                    float* __restrict__ out) {
    __shared__ float sg[3 * 4 * 512 + 8];   // [ch][cell][512], pad for b=7 pair
    int tx = blockIdx.x, ty = blockIdx.y;   // 64 x 64 tiles

    {
        const float4* g4 = (const float4*)grid;
        float4* s4 = (float4*)sg;
        #pragma unroll
        for (int it = 0; it < 2; ++it) {
            int i = threadIdx.x + it * 256;       // float4 index within a channel plane [0,512)
            int cell = i >> 7;                    // 0..3 = (dy<<1)|dx
            int ci4 = i & 127;
            int cy = ty + 2 + (cell >> 1), cx = tx + 2 + (cell & 1);
            long cbase4 = ((long)(cy * kSW + cx)) << 7;   // 128 float4 per cell
            #pragma unroll
            for (int ch = 0; ch < 3; ++ch)
                s4[ch * 512 + i] = g4[(long)ch * (kT3 / 4) + cbase4 + ci4];
        }
    }
    __syncthreads();

    const int* ip = (const int*)(hdrF + 8);
    int d3[3] = {ip[0], ip[1], ip[2]};
    int lx = threadIdx.x & 15, ly = threadIdx.x >> 4;
    int y = (ty << 4) + ly, x = (tx << 4) + lx;
    int p = (y << 10) + x;

    float ya = (float)ly * 0.0625f;   // exact fractional part of y/16
    float xa = (float)lx * 0.0625f;

    int li[3], ri[3];
    float al[3];
    #pragma unroll
    for (int c = 0; c < 3; ++c) {
        float v0 = feat[p * 3 + c] - hdrF[c];
        float sv = v0 * 4.0f + 2.0f;
        int l = (int)sv;
        int dm = d3[c] - 1;
        l = l < 0 ? 0 : (l > dm ? dm : l);
        int rr = l + 1 > dm ? dm : l + 1;
        li[c] = l; ri[c] = rr; al[c] = sv - (float)l;
    }

    float spw[4];
    {
        float wy[2] = {1.0f - ya, ya};
        float wx[2] = {1.0f - xa, xa};
        spw[0] = wy[0] * wx[0]; spw[1] = wy[0] * wx[1];
        spw[2] = wy[1] * wx[0]; spw[3] = wy[1] * wx[1];
    }
    int rs[2] = {li[0], ri[0]}; float wrr[2] = {1.0f - al[0], al[0]};
    int gs[2] = {li[1], ri[1]}; float wgg[2] = {1.0f - al[1], al[1]};
    int bq = li[2];
    float aeff = (ri[2] > li[2]) ? al[2] : 0.0f;

    float acc0 = 0.0f, acc1 = 0.0f, acc2 = 0.0f;
    #pragma unroll
    for (int k = 0; k < 4; ++k) {
        #pragma unroll
        for (int cr = 0; cr < 2; ++cr)
        #pragma unroll
        for (int cg = 0; cg < 2; ++cg) {
            int si = (k << 9) + (rs[cr] << 6) + (gs[cg] << 3) + bq;
            float w = spw[k] * wrr[cr] * wgg[cg];
            float a0 = sg[si],        a1 = sg[si + 1];
            float b0 = sg[2048 + si], b1 = sg[2048 + si + 1];
            float c0 = sg[4096 + si], c1 = sg[4096 + si + 1];
            acc0 += w * (a0 + aeff * (a1 - a0));
            acc1 += w * (b0 + aeff * (b1 - b0));
            acc2 += w * (c0 + aeff * (c1 - c0));
        }
    }
    out[p * 3 + 0] = acc0;
    out[p * 3 + 1] = acc1;
    out[p * 3 + 2] = acc2;
}

}  // namespace

extern "C" void kernel_launch(void* const* d_in, const int* in_sizes, int n_in,
                              void* d_out, int out_size, void* d_ws, size_t ws_size,
                              hipStream_t stream) {
    const float* feat = (const float*)d_in[0];
    const float* inp  = (const float*)d_in[1];
    float* out = (float*)d_out;

    float* hdrF  = (float*)d_ws;
    float* part  = (float*)((char*)d_ws + 1024);       // 1024 x 6 floats = 24 KB
    float* gridA = (float*)((char*)d_ws + 32768);      // splat, transposed cells
    float* gridB = gridA + 3 * (size_t)kT3;            // blurred, standard cells

    minmax_kernel<<<1024, 256, 0, stream>>>(feat, part);
    params_kernel<<<1, 256, 0, stream>>>(part, hdrF);

    splat_kernel<<<dim3(65, 65), 256, 0, stream>>>(feat, inp, hdrF, gridA);
    blur2_kernel<<<dim3(65, 65), 192, 0, stream>>>(gridB, gridA, hdrF);
    slice_kernel<<<dim3(64, 64), 256, 0, stream>>>(feat, hdrF, gridB, out);
}